// Round 1
// baseline (1429.153 us; speedup 1.0000x reference)
//
#include <hip/hip_runtime.h>

#define N_NODES 50000
#define N_EDGES 1600000
#define ND 16
#define ED 16
#define HID 64
#define M1 (2*ND+ED)   // 48
#define M2 (ND+ED)     // 32

// ---------------- edge kernel: e_new = fR(concat(x[dst], x[src], e)); agg[dst] += e_new
__global__ __launch_bounds__(256) void edge_kernel(
    const float* __restrict__ x,      // [N, 16]
    const int*   __restrict__ ei,     // [2, E]
    const float* __restrict__ e,      // [E, 16]
    const float* __restrict__ W1,     // [48, 64]
    const float* __restrict__ b1,     // [64]
    const float* __restrict__ W2,     // [64, 16]
    const float* __restrict__ b2,     // [16]
    float* __restrict__ e_new,        // [E, 16]
    float* __restrict__ agg)          // [N, 16]
{
    int idx = blockIdx.x * blockDim.x + threadIdx.x;
    if (idx >= N_EDGES) return;
    int src = ei[idx];
    int dst = ei[N_EDGES + idx];

    float m[M1];
    {
        const float4* xd = reinterpret_cast<const float4*>(x) + dst * 4;
        const float4* xs = reinterpret_cast<const float4*>(x) + src * 4;
        const float4* ep = reinterpret_cast<const float4*>(e) + (size_t)idx * 4;
#pragma unroll
        for (int q = 0; q < 4; ++q) {
            float4 v = xd[q];
            m[4*q+0] = v.x; m[4*q+1] = v.y; m[4*q+2] = v.z; m[4*q+3] = v.w;
        }
#pragma unroll
        for (int q = 0; q < 4; ++q) {
            float4 v = xs[q];
            m[16+4*q+0] = v.x; m[16+4*q+1] = v.y; m[16+4*q+2] = v.z; m[16+4*q+3] = v.w;
        }
#pragma unroll
        for (int q = 0; q < 4; ++q) {
            float4 v = ep[q];
            m[32+4*q+0] = v.x; m[32+4*q+1] = v.y; m[32+4*q+2] = v.z; m[32+4*q+3] = v.w;
        }
    }

    // layer 1: h = relu(m @ W1 + b1), W1 rows contiguous -> scalar loads
    float h[HID];
#pragma unroll
    for (int j = 0; j < HID; ++j) h[j] = b1[j];
#pragma unroll 4
    for (int i = 0; i < M1; ++i) {
        float mi = m[i];
        const float* wr = W1 + i * HID;
#pragma unroll
        for (int j = 0; j < HID; ++j) h[j] = fmaf(mi, wr[j], h[j]);
    }

    // layer 2: o = relu(h) @ W2 + b2
    float o[ED];
#pragma unroll
    for (int k = 0; k < ED; ++k) o[k] = b2[k];
#pragma unroll 8
    for (int j = 0; j < HID; ++j) {
        float hj = fmaxf(h[j], 0.0f);
        const float* wr = W2 + j * ED;
#pragma unroll
        for (int k = 0; k < ED; ++k) o[k] = fmaf(hj, wr[k], o[k]);
    }

    float4* op = reinterpret_cast<float4*>(e_new) + (size_t)idx * 4;
    op[0] = make_float4(o[0], o[1], o[2],  o[3]);
    op[1] = make_float4(o[4], o[5], o[6],  o[7]);
    op[2] = make_float4(o[8], o[9], o[10], o[11]);
    op[3] = make_float4(o[12], o[13], o[14], o[15]);

    float* ag = agg + (size_t)dst * ED;
#pragma unroll
    for (int k = 0; k < ED; ++k) atomicAdd(ag + k, o[k]);
}

// ---------------- node kernel: x_new = fO(concat(x, agg))
__global__ __launch_bounds__(256) void node_kernel(
    const float* __restrict__ x,      // [N, 16]
    const float* __restrict__ agg,    // [N, 16]
    const float* __restrict__ W1,     // [32, 64]
    const float* __restrict__ b1,     // [64]
    const float* __restrict__ W2,     // [64, 16]
    const float* __restrict__ b2,     // [16]
    float* __restrict__ x_new)        // [N, 16]
{
    int idx = blockIdx.x * blockDim.x + threadIdx.x;
    if (idx >= N_NODES) return;

    float m[M2];
    {
        const float4* xp = reinterpret_cast<const float4*>(x) + idx * 4;
        const float4* ap = reinterpret_cast<const float4*>(agg) + idx * 4;
#pragma unroll
        for (int q = 0; q < 4; ++q) {
            float4 v = xp[q];
            m[4*q+0] = v.x; m[4*q+1] = v.y; m[4*q+2] = v.z; m[4*q+3] = v.w;
        }
#pragma unroll
        for (int q = 0; q < 4; ++q) {
            float4 v = ap[q];
            m[16+4*q+0] = v.x; m[16+4*q+1] = v.y; m[16+4*q+2] = v.z; m[16+4*q+3] = v.w;
        }
    }

    float h[HID];
#pragma unroll
    for (int j = 0; j < HID; ++j) h[j] = b1[j];
#pragma unroll 4
    for (int i = 0; i < M2; ++i) {
        float mi = m[i];
        const float* wr = W1 + i * HID;
#pragma unroll
        for (int j = 0; j < HID; ++j) h[j] = fmaf(mi, wr[j], h[j]);
    }

    float o[ED];
#pragma unroll
    for (int k = 0; k < ED; ++k) o[k] = b2[k];
#pragma unroll 8
    for (int j = 0; j < HID; ++j) {
        float hj = fmaxf(h[j], 0.0f);
        const float* wr = W2 + j * ED;
#pragma unroll
        for (int k = 0; k < ED; ++k) o[k] = fmaf(hj, wr[k], o[k]);
    }

    float4* op = reinterpret_cast<float4*>(x_new) + idx * 4;
    op[0] = make_float4(o[0], o[1], o[2],  o[3]);
    op[1] = make_float4(o[4], o[5], o[6],  o[7]);
    op[2] = make_float4(o[8], o[9], o[10], o[11]);
    op[3] = make_float4(o[12], o[13], o[14], o[15]);
}

extern "C" void kernel_launch(void* const* d_in, const int* in_sizes, int n_in,
                              void* d_out, int out_size, void* d_ws, size_t ws_size,
                              hipStream_t stream) {
    const float* x     = (const float*)d_in[0];
    const int*   ei    = (const int*)  d_in[1];
    const float* e     = (const float*)d_in[2];
    const float* fR_W1 = (const float*)d_in[3];
    const float* fR_b1 = (const float*)d_in[4];
    const float* fR_W2 = (const float*)d_in[5];
    const float* fR_b2 = (const float*)d_in[6];
    const float* fO_W1 = (const float*)d_in[7];
    const float* fO_b1 = (const float*)d_in[8];
    const float* fO_W2 = (const float*)d_in[9];
    const float* fO_b2 = (const float*)d_in[10];

    float* x_new = (float*)d_out;                               // [N, 16]
    float* e_new = (float*)d_out + (size_t)N_NODES * ND;        // [E, 16]
    float* agg   = (float*)d_ws;                                // [N, 16]

    hipMemsetAsync(agg, 0, (size_t)N_NODES * ED * sizeof(float), stream);

    edge_kernel<<<N_EDGES / 256, 256, 0, stream>>>(
        x, ei, e, fR_W1, fR_b1, fR_W2, fR_b2, e_new, agg);

    node_kernel<<<(N_NODES + 255) / 256, 256, 0, stream>>>(
        x, agg, fO_W1, fO_b1, fO_W2, fO_b2, x_new);
}